// Round 12
// baseline (155.600 us; speedup 1.0000x reference)
//
#include <hip/hip_runtime.h>
#include <cstdint>
#include <cstddef>

#define NODES 20000
#define NEDGE 320000
#define CAP 64            // padded CSR capacity per node (max deg ~34 at 16+/-4)
#define NEB 1250          // NEDGE/256
#define LINB 16           // 4096/256
#define BIGB 32           // 8192/256
#define XB   5000         // NODES*64/256

using bf16x8 = __attribute__((ext_vector_type(8))) __bf16;
using f32x4  = __attribute__((ext_vector_type(4))) float;
using f32x2  = __attribute__((ext_vector_type(2))) float;

__device__ __forceinline__ unsigned short f2bf(float f) {
  union { float f; unsigned int u; } v; v.f = f;
  unsigned int r = v.u + 0x7FFF + ((v.u >> 16) & 1);  // RNE
  return (unsigned short)(r >> 16);
}

// ------- build: padded-CSR fill | x->fp8 encode | lin->bf16 | BigW (all concurrent) -------
// cnt zeroed by hipMemsetAsync before this kernel.
// wb16 layout: [0,4096) lin ; [4096,12288) BigW[128][64]
__global__ void k_build(const int* __restrict__ ei, int* __restrict__ cnt,
                        int* __restrict__ csr, const float* __restrict__ x,
                        unsigned int* __restrict__ xs8,
                        const float* __restrict__ lin, const float* __restrict__ u1,
                        const float* __restrict__ u2, const float* __restrict__ l1,
                        const float* __restrict__ l2, const float* __restrict__ lastw,
                        unsigned short* __restrict__ wb16) {
  __shared__ float tmp_u[4][64];
  __shared__ float tmp_l[4][64];
  int bid = blockIdx.x, t = threadIdx.x;
  if (bid < NEB) {
    int i = bid * 256 + t;
    if (i < NEDGE) {
      int row = ei[i];
      int col = ei[NEDGE + i];
      int pos = atomicAdd(&cnt[col], 1);
      if (pos < CAP) csr[col * CAP + pos] = row;
    }
  } else if (bid < NEB + XB) {
    int g = (bid - NEB) * 256 + t;  // [0, NODES*64)
    int n = g >> 6, i = g & 63;
    int b = i >> 4, c = (i & 15) * 4;
    f32x4 v = __builtin_nontemporal_load(
        (const f32x4*)(x + ((size_t)b * NODES + n) * 64 + c));
    int p = 0;
    p = __builtin_amdgcn_cvt_pk_fp8_f32(v.x, v.y, p, false);  // bytes 0,1
    p = __builtin_amdgcn_cvt_pk_fp8_f32(v.z, v.w, p, true);   // bytes 2,3
    xs8[(size_t)n * 64 + i] = (unsigned int)p;
  } else if (bid < NEB + XB + LINB) {
    int g = (bid - NEB - XB) * 256 + t;  // [0,4096)
    wb16[g] = f2bf(lin[g]);
  } else {
    // BigW[o][j] = sum_p (sum_k last[o][k] u2[k][p]) u1[p][j]
    //            + sum_p (sum_k last[o][64+k] l2[k][p]) l1[p][j]
    int o0 = (bid - NEB - XB - LINB) * 4;
    int ol = t >> 6, p = t & 63;
    float su = 0.f, sl = 0.f;
    for (int k = 0; k < 64; ++k) {
      float lu = lastw[(o0 + ol) * 128 + k];
      float ll = lastw[(o0 + ol) * 128 + 64 + k];
      su += lu * u2[k * 64 + p];
      sl += ll * l2[k * 64 + p];
    }
    tmp_u[ol][p] = su;
    tmp_l[ol][p] = sl;
    __syncthreads();
    int j = p;
    float acc = 0.f;
    for (int q = 0; q < 64; ++q)
      acc += tmp_u[ol][q] * u1[q * 64 + j] + tmp_l[ol][q] * l1[q * 64 + j];
    wb16[4096 + (o0 + ol) * 64 + j] = f2bf(acc);
  }
}

// ---------------- fused gather(fp8, on-the-fly dis) + lin + sigmoid + BigW + relu ----------------
// block = 16 nodes (64 rows), 4 waves (256 thr); wave gathers 4 nodes serially.
// stage1 (swapped): h^T[feat][row] = lin @ xa^T; fst = sigmoid -> LDS packed
// stage2 (natural): D[row][oc] = fst @ BigW^T; oc = lane&15 -> full-line nt stores
__global__ __launch_bounds__(256) void k_gpost(const int* __restrict__ cnt,
                                               const int* __restrict__ csr,
                                               const unsigned int* __restrict__ xs8,
                                               const float* __restrict__ bias,
                                               const unsigned short* __restrict__ wb16,
                                               float* __restrict__ out) {
  __shared__ unsigned short xa[64][72];
  __shared__ unsigned short fst[64][72];
  int t = threadIdx.x;
  int w = t >> 6, l = t & 63;
  int n0 = blockIdx.x * 16;

  // gather phase: wave w handles nodes n0+4w .. n0+4w+3; lane = 4 fp8 channels (1 dword)
  for (int j = 0; j < 4; ++j) {
    int n = n0 + 4 * w + j;
    int cv = cnt[n];
    int dn = cv > CAP ? CAP : cv;
    float dsn = rsqrtf((float)(cv + 1));  // +1 = self loop
    int beg = n * CAP, end = beg + dn;
    float a0, a1, a2, a3;
    {
      unsigned int u = xs8[(size_t)n * 64 + l];  // self loop
      f32x2 lo = __builtin_amdgcn_cvt_pk_f32_fp8(u, false);
      f32x2 hi = __builtin_amdgcn_cvt_pk_f32_fp8(u, true);
      a0 = dsn * lo.x; a1 = dsn * lo.y; a2 = dsn * hi.x; a3 = dsn * hi.y;
    }
    int i = beg;
    for (; i + 8 <= end; i += 8) {  // 8-deep ILP
      int r0 = csr[i],     r1 = csr[i + 1], r2 = csr[i + 2], r3 = csr[i + 3];
      int r4 = csr[i + 4], r5 = csr[i + 5], r6 = csr[i + 6], r7 = csr[i + 7];
      unsigned int u0 = xs8[(size_t)r0 * 64 + l];
      unsigned int u1 = xs8[(size_t)r1 * 64 + l];
      unsigned int u2 = xs8[(size_t)r2 * 64 + l];
      unsigned int u3 = xs8[(size_t)r3 * 64 + l];
      unsigned int u4 = xs8[(size_t)r4 * 64 + l];
      unsigned int u5 = xs8[(size_t)r5 * 64 + l];
      unsigned int u6 = xs8[(size_t)r6 * 64 + l];
      unsigned int u7 = xs8[(size_t)r7 * 64 + l];
      int c0 = cnt[r0], c1 = cnt[r1], c2 = cnt[r2], c3 = cnt[r3];
      int c4 = cnt[r4], c5 = cnt[r5], c6 = cnt[r6], c7 = cnt[r7];
#pragma unroll
      for (int e = 0; e < 8; ++e) {
        unsigned int u = e == 0 ? u0 : e == 1 ? u1 : e == 2 ? u2 : e == 3 ? u3
                       : e == 4 ? u4 : e == 5 ? u5 : e == 6 ? u6 : u7;
        int cc = e == 0 ? c0 : e == 1 ? c1 : e == 2 ? c2 : e == 3 ? c3
               : e == 4 ? c4 : e == 5 ? c5 : e == 6 ? c6 : c7;
        float d = rsqrtf((float)(cc + 1));
        f32x2 lo = __builtin_amdgcn_cvt_pk_f32_fp8(u, false);
        f32x2 hi = __builtin_amdgcn_cvt_pk_f32_fp8(u, true);
        a0 += d * lo.x; a1 += d * lo.y; a2 += d * hi.x; a3 += d * hi.y;
      }
    }
    for (; i < end; ++i) {
      int r = csr[i];
      unsigned int u = xs8[(size_t)r * 64 + l];
      float d = rsqrtf((float)(cnt[r] + 1));
      f32x2 lo = __builtin_amdgcn_cvt_pk_f32_fp8(u, false);
      f32x2 hi = __builtin_amdgcn_cvt_pk_f32_fp8(u, true);
      a0 += d * lo.x; a1 += d * lo.y; a2 += d * hi.x; a3 += d * hi.y;
    }
    ushort4 o;
    o.x = f2bf(a0); o.y = f2bf(a1); o.z = f2bf(a2); o.w = f2bf(a3);
    // row = node_local*4 + batch; node_local = 4w+j, batch = l>>4
    *(ushort4*)&xa[16 * w + 4 * j + (l >> 4)][(l & 15) * 4] = o;
  }
  __syncthreads();

  int m = l & 15, q = l >> 4;
  const unsigned short* wlin = wb16;
  const unsigned short* bigw = wb16 + 4096;

  // stage1 (swapped): D[feat=16w+4q+reg][row=16nt+m]; fst = sigmoid(h*dis+bias)
  {
    f32x4 acc1[4] = {{0,0,0,0},{0,0,0,0},{0,0,0,0},{0,0,0,0}};
#pragma unroll
    for (int kk = 0; kk < 2; ++kk) {
      bf16x8 a = *(const bf16x8*)(wlin + (16 * w + m) * 64 + q * 8 + 32 * kk);
#pragma unroll
      for (int nt = 0; nt < 4; ++nt) {
        bf16x8 b = *(const bf16x8*)&xa[16 * nt + m][q * 8 + 32 * kk];
        acc1[nt] = __builtin_amdgcn_mfma_f32_16x16x32_bf16(a, b, acc1[nt], 0, 0, 0);
      }
    }
    float4 b4 = *(const float4*)(bias + 16 * w + 4 * q);
#pragma unroll
    for (int nt = 0; nt < 4; ++nt) {
      int row = 16 * nt + m;
      int n = n0 + (row >> 2);
      float ds = rsqrtf((float)(cnt[n] + 1));
      float v0 = acc1[nt][0] * ds + b4.x;
      float v1 = acc1[nt][1] * ds + b4.y;
      float v2 = acc1[nt][2] * ds + b4.z;
      float v3 = acc1[nt][3] * ds + b4.w;
      ushort4 o;
      o.x = f2bf(1.f / (1.f + __expf(-v0)));
      o.y = f2bf(1.f / (1.f + __expf(-v1)));
      o.z = f2bf(1.f / (1.f + __expf(-v2)));
      o.w = f2bf(1.f / (1.f + __expf(-v3)));
      *(ushort4*)&fst[row][16 * w + 4 * q] = o;
    }
  }
  __syncthreads();

  // stage2 (natural): D[row=16nt+4q+reg][oc=32w+16mt+m] -> full-line nt stores
  {
    f32x4 acc2[2][4] = {{{0,0,0,0},{0,0,0,0},{0,0,0,0},{0,0,0,0}},
                        {{0,0,0,0},{0,0,0,0},{0,0,0,0},{0,0,0,0}}};
#pragma unroll
    for (int kk = 0; kk < 2; ++kk) {
#pragma unroll
      for (int nt = 0; nt < 4; ++nt) {
        bf16x8 a = *(const bf16x8*)&fst[16 * nt + m][q * 8 + 32 * kk];
#pragma unroll
        for (int mt = 0; mt < 2; ++mt) {
          bf16x8 b = *(const bf16x8*)(bigw + (32 * w + 16 * mt + m) * 64 + q * 8 + 32 * kk);
          acc2[mt][nt] = __builtin_amdgcn_mfma_f32_16x16x32_bf16(a, b, acc2[mt][nt], 0, 0, 0);
        }
      }
    }
#pragma unroll
    for (int mt = 0; mt < 2; ++mt)
#pragma unroll
      for (int nt = 0; nt < 4; ++nt)
#pragma unroll
        for (int r = 0; r < 4; ++r) {
          int row = 16 * nt + 4 * q + r;  // lanes m=0..15 share this row
          int n = n0 + (row >> 2), b = row & 3;
          float v = acc2[mt][nt][r];
          __builtin_nontemporal_store(
              v > 0.f ? v : 0.f,
              out + ((size_t)b * NODES + n) * 128 + 32 * w + 16 * mt + m);
        }
  }
}

extern "C" void kernel_launch(void* const* d_in, const int* in_sizes, int n_in,
                              void* d_out, int out_size, void* d_ws, size_t ws_size,
                              hipStream_t stream) {
  const float* x     = (const float*)d_in[0];
  const int*   ei    = (const int*)d_in[1];
  const float* lin_w = (const float*)d_in[2];
  const float* bias  = (const float*)d_in[3];
  const float* up1   = (const float*)d_in[4];
  const float* up2   = (const float*)d_in[5];
  const float* lo1   = (const float*)d_in[6];
  const float* lo2   = (const float*)d_in[7];
  const float* lastw = (const float*)d_in[8];
  float* out = (float*)d_out;

  char* ws = (char*)d_ws;
  unsigned short* wb16 = (unsigned short*)(ws);            // 24576 B
  int*   cnt        = (int*)(ws + (192 << 10));            // 80 KB
  int*   csr        = (int*)(ws + (1 << 20));              // NODES*CAP*4 = 5.12 MB
  unsigned int* xs8 = (unsigned int*)(ws + (8 << 20));     // NODES*256 B = 5.12 MB

  (void)hipMemsetAsync(cnt, 0, NODES * sizeof(int), stream);
  k_build<<<NEB + XB + LINB + BIGB, 256, 0, stream>>>(ei, cnt, csr, x, xs8, lin_w,
                                                      up1, up2, lo1, lo2, lastw, wb16);
  k_gpost<<<NODES / 16, 256, 0, stream>>>(cnt, csr, xs8, bias, wb16, out);
}

// Round 13
// 145.683 us; speedup vs baseline: 1.0681x; 1.0681x over previous
//
#include <hip/hip_runtime.h>
#include <cstdint>
#include <cstddef>

#define NODES 20000
#define NEDGE 320000
#define CAP 64            // padded CSR capacity per node (max deg ~34 at 16+/-4)
#define NEB 1250          // NEDGE/256
#define LINB 16           // 4096/256
#define BIGB 32           // 8192/256

using bf16x8 = __attribute__((ext_vector_type(8))) __bf16;
using f32x4  = __attribute__((ext_vector_type(4))) float;
using f32x2  = __attribute__((ext_vector_type(2))) float;

__device__ __forceinline__ unsigned short f2bf(float f) {
  union { float f; unsigned int u; } v; v.f = f;
  unsigned int r = v.u + 0x7FFF + ((v.u >> 16) & 1);  // RNE
  return (unsigned short)(r >> 16);
}

// ---------------- build: padded-CSR fill + lin->bf16 + BigW (direct) ----------------
// cnt zeroed by hipMemsetAsync before this kernel.
// wb16 layout: [0,4096) lin ; [4096,12288) BigW[128][64]
__global__ void k_build(const int* __restrict__ ei, int* __restrict__ cnt,
                        int* __restrict__ csr,
                        const float* __restrict__ lin, const float* __restrict__ u1,
                        const float* __restrict__ u2, const float* __restrict__ l1,
                        const float* __restrict__ l2, const float* __restrict__ lastw,
                        unsigned short* __restrict__ wb16) {
  __shared__ float tmp_u[4][64];
  __shared__ float tmp_l[4][64];
  int bid = blockIdx.x, t = threadIdx.x;
  if (bid < NEB) {
    int i = bid * 256 + t;
    if (i < NEDGE) {
      int row = ei[i];
      int col = ei[NEDGE + i];
      int pos = atomicAdd(&cnt[col], 1);
      if (pos < CAP) csr[col * CAP + pos] = row;
    }
  } else if (bid < NEB + LINB) {
    int g = (bid - NEB) * 256 + t;  // [0,4096)
    wb16[g] = f2bf(lin[g]);
  } else {
    // BigW[o][j] = sum_p (sum_k last[o][k] u2[k][p]) u1[p][j]
    //            + sum_p (sum_k last[o][64+k] l2[k][p]) l1[p][j]
    int o0 = (bid - NEB - LINB) * 4;
    int ol = t >> 6, p = t & 63;
    float su = 0.f, sl = 0.f;
    for (int k = 0; k < 64; ++k) {
      float lu = lastw[(o0 + ol) * 128 + k];
      float ll = lastw[(o0 + ol) * 128 + 64 + k];
      su += lu * u2[k * 64 + p];
      sl += ll * l2[k * 64 + p];
    }
    tmp_u[ol][p] = su;
    tmp_l[ol][p] = sl;
    __syncthreads();
    int j = p;
    float acc = 0.f;
    for (int q = 0; q < 64; ++q)
      acc += tmp_u[ol][q] * u1[q * 64 + j] + tmp_l[ol][q] * l1[q * 64 + j];
    wb16[4096 + (o0 + ol) * 64 + j] = f2bf(acc);
  }
}

// ---------------- xconv: dis = rsqrt(cnt+1); xs8 = fp8(x * dis) ----------------
__global__ void k_xconv(const int* __restrict__ cnt, float* __restrict__ dis,
                        const float* __restrict__ x, unsigned int* __restrict__ xs8) {
  int g = blockIdx.x * 256 + threadIdx.x;  // [0, NODES*64)
  int n = g >> 6, i = g & 63;
  int b = i >> 4, c = (i & 15) * 4;
  float ds = rsqrtf((float)(cnt[n] + 1));  // +1 = self loop
  if (i == 0) dis[n] = ds;
  f32x4 v = __builtin_nontemporal_load(
      (const f32x4*)(x + ((size_t)b * NODES + n) * 64 + c));
  int p = 0;
  p = __builtin_amdgcn_cvt_pk_fp8_f32(v.x * ds, v.y * ds, p, false);  // bytes 0,1
  p = __builtin_amdgcn_cvt_pk_fp8_f32(v.z * ds, v.w * ds, p, true);   // bytes 2,3
  xs8[(size_t)n * 64 + i] = (unsigned int)p;
}

// ---------------- fused gather(fp8) + lin + sigmoid + BigW + relu ----------------
// block = 8 nodes (32 rows), 4 waves (256 thr); wave gathers 2 nodes serially.
// stage1 (swapped): h^T[feat][row] = lin @ xa^T; fst = sigmoid -> LDS packed
// stage2 (natural): D[row][oc] = fst @ BigW^T; oc = lane&15 -> full-line stores
__global__ __launch_bounds__(256) void k_gpost(const int* __restrict__ cnt,
                                               const int* __restrict__ csr,
                                               const unsigned int* __restrict__ xs8,
                                               const float* __restrict__ dis,
                                               const float* __restrict__ bias,
                                               const unsigned short* __restrict__ wb16,
                                               float* __restrict__ out) {
  __shared__ unsigned short xa[32][72];
  __shared__ unsigned short fst[32][72];
  int t = threadIdx.x;
  int w = t >> 6, l = t & 63;
  int n0 = blockIdx.x * 8;

  // gather phase: wave w handles nodes n0+2w, n0+2w+1; lane = 4 fp8 channels (1 dword)
  for (int j = 0; j < 2; ++j) {
    int n = n0 + 2 * w + j;
    int dn = cnt[n]; if (dn > CAP) dn = CAP;
    int beg = n * CAP, end = beg + dn;
    float a0, a1, a2, a3;
    {
      unsigned int u = xs8[(size_t)n * 64 + l];  // self loop
      f32x2 lo = __builtin_amdgcn_cvt_pk_f32_fp8(u, false);
      f32x2 hi = __builtin_amdgcn_cvt_pk_f32_fp8(u, true);
      a0 = lo.x; a1 = lo.y; a2 = hi.x; a3 = hi.y;
    }
    int i = beg;
    for (; i + 8 <= end; i += 8) {  // 8-deep ILP
      int r0 = csr[i],     r1 = csr[i + 1], r2 = csr[i + 2], r3 = csr[i + 3];
      int r4 = csr[i + 4], r5 = csr[i + 5], r6 = csr[i + 6], r7 = csr[i + 7];
      unsigned int u0 = xs8[(size_t)r0 * 64 + l];
      unsigned int u1 = xs8[(size_t)r1 * 64 + l];
      unsigned int u2 = xs8[(size_t)r2 * 64 + l];
      unsigned int u3 = xs8[(size_t)r3 * 64 + l];
      unsigned int u4 = xs8[(size_t)r4 * 64 + l];
      unsigned int u5 = xs8[(size_t)r5 * 64 + l];
      unsigned int u6 = xs8[(size_t)r6 * 64 + l];
      unsigned int u7 = xs8[(size_t)r7 * 64 + l];
#pragma unroll
      for (int e = 0; e < 8; ++e) {
        unsigned int u = e == 0 ? u0 : e == 1 ? u1 : e == 2 ? u2 : e == 3 ? u3
                       : e == 4 ? u4 : e == 5 ? u5 : e == 6 ? u6 : u7;
        f32x2 lo = __builtin_amdgcn_cvt_pk_f32_fp8(u, false);
        f32x2 hi = __builtin_amdgcn_cvt_pk_f32_fp8(u, true);
        a0 += lo.x; a1 += lo.y; a2 += hi.x; a3 += hi.y;
      }
    }
    for (; i < end; ++i) {
      unsigned int u = xs8[(size_t)csr[i] * 64 + l];
      f32x2 lo = __builtin_amdgcn_cvt_pk_f32_fp8(u, false);
      f32x2 hi = __builtin_amdgcn_cvt_pk_f32_fp8(u, true);
      a0 += lo.x; a1 += lo.y; a2 += hi.x; a3 += hi.y;
    }
    ushort4 o;
    o.x = f2bf(a0); o.y = f2bf(a1); o.z = f2bf(a2); o.w = f2bf(a3);
    // row = node_local*4 + batch; node_local = 2w+j, batch = l>>4
    *(ushort4*)&xa[(2 * w + j) * 4 + (l >> 4)][(l & 15) * 4] = o;
  }
  __syncthreads();

  int m = l & 15, q = l >> 4;
  const unsigned short* wlin = wb16;
  const unsigned short* bigw = wb16 + 4096;

  // stage1 (swapped): D[feat=16w+4q+reg][row=16nt+m]; fst = sigmoid(h*dis+bias)
  {
    f32x4 acc1[2] = {{0,0,0,0},{0,0,0,0}};
#pragma unroll
    for (int kk = 0; kk < 2; ++kk) {
      bf16x8 a = *(const bf16x8*)(wlin + (16 * w + m) * 64 + q * 8 + 32 * kk);
#pragma unroll
      for (int nt = 0; nt < 2; ++nt) {
        bf16x8 b = *(const bf16x8*)&xa[16 * nt + m][q * 8 + 32 * kk];
        acc1[nt] = __builtin_amdgcn_mfma_f32_16x16x32_bf16(a, b, acc1[nt], 0, 0, 0);
      }
    }
    float4 b4 = *(const float4*)(bias + 16 * w + 4 * q);
#pragma unroll
    for (int nt = 0; nt < 2; ++nt) {
      int row = 16 * nt + m;
      float ds = dis[n0 + (row >> 2)];
      float v0 = acc1[nt][0] * ds + b4.x;
      float v1 = acc1[nt][1] * ds + b4.y;
      float v2 = acc1[nt][2] * ds + b4.z;
      float v3 = acc1[nt][3] * ds + b4.w;
      ushort4 o;
      o.x = f2bf(1.f / (1.f + __expf(-v0)));
      o.y = f2bf(1.f / (1.f + __expf(-v1)));
      o.z = f2bf(1.f / (1.f + __expf(-v2)));
      o.w = f2bf(1.f / (1.f + __expf(-v3)));
      *(ushort4*)&fst[row][16 * w + 4 * q] = o;
    }
  }
  __syncthreads();

  // stage2 (natural): D[row=16nt+4q+reg][oc=32w+16mt+m] -> full-line stores
  {
    f32x4 acc2[2][2] = {{{0,0,0,0},{0,0,0,0}},{{0,0,0,0},{0,0,0,0}}};
#pragma unroll
    for (int kk = 0; kk < 2; ++kk) {
#pragma unroll
      for (int nt = 0; nt < 2; ++nt) {
        bf16x8 a = *(const bf16x8*)&fst[16 * nt + m][q * 8 + 32 * kk];
#pragma unroll
        for (int mt = 0; mt < 2; ++mt) {
          bf16x8 b = *(const bf16x8*)(bigw + (32 * w + 16 * mt + m) * 64 + q * 8 + 32 * kk);
          acc2[mt][nt] = __builtin_amdgcn_mfma_f32_16x16x32_bf16(a, b, acc2[mt][nt], 0, 0, 0);
        }
      }
    }
#pragma unroll
    for (int mt = 0; mt < 2; ++mt)
#pragma unroll
      for (int nt = 0; nt < 2; ++nt)
#pragma unroll
        for (int r = 0; r < 4; ++r) {
          int row = 16 * nt + 4 * q + r;  // lanes m=0..15 share this row
          int n = n0 + (row >> 2), b = row & 3;
          float v = acc2[mt][nt][r];
          out[((size_t)b * NODES + n) * 128 + 32 * w + 16 * mt + m] = v > 0.f ? v : 0.f;
        }
  }
}

extern "C" void kernel_launch(void* const* d_in, const int* in_sizes, int n_in,
                              void* d_out, int out_size, void* d_ws, size_t ws_size,
                              hipStream_t stream) {
  const float* x     = (const float*)d_in[0];
  const int*   ei    = (const int*)d_in[1];
  const float* lin_w = (const float*)d_in[2];
  const float* bias  = (const float*)d_in[3];
  const float* up1   = (const float*)d_in[4];
  const float* up2   = (const float*)d_in[5];
  const float* lo1   = (const float*)d_in[6];
  const float* lo2   = (const float*)d_in[7];
  const float* lastw = (const float*)d_in[8];
  float* out = (float*)d_out;

  char* ws = (char*)d_ws;
  unsigned short* wb16 = (unsigned short*)(ws);            // 24576 B
  float* dis        = (float*)(ws + (64 << 10));           // 80 KB
  int*   cnt        = (int*)(ws + (192 << 10));            // 80 KB
  int*   csr        = (int*)(ws + (1 << 20));              // NODES*CAP*4 = 5.12 MB
  unsigned int* xs8 = (unsigned int*)(ws + (8 << 20));     // NODES*256 B = 5.12 MB

  (void)hipMemsetAsync(cnt, 0, NODES * sizeof(int), stream);
  k_build<<<NEB + LINB + BIGB, 256, 0, stream>>>(ei, cnt, csr, lin_w, up1, up2,
                                                 lo1, lo2, lastw, wb16);
  k_xconv<<<NODES / 4, 256, 0, stream>>>(cnt, dis, x, xs8);
  k_gpost<<<NODES / 8, 256, 0, stream>>>(cnt, csr, xs8, dis, bias, wb16, out);
}